// Round 5
// baseline (252.284 us; speedup 1.0000x reference)
//
#include <hip/hip_runtime.h>
#include <math.h>
#include <stdint.h>

// ChebConv GNN: N=50000, E=800000, F=H=64, C=10.
//   degS[i] = out-degree of i ; dis = rsqrt(degS) (0 if 0)
//   h  = relu(x @ W1 + b1)
//   p0 = h @ W20 + b2 ;  g = h @ W21
//   lap[dst] = sum_e -(dis[src]*dis[dst]) * g[src]   (CSR gather)
//   out = log_softmax( (relu(p0 + lap) + h) @ Wl + bl )
//
// Build: two-level LDS counting sort (no random global atomics).
//   Phase A: bin edges by dst>>8 into 256 bucket regions (coalesced flush).
//   Phase B: per bucket (<=256 dsts), LDS histogram+scan -> CSR, rowptr, cntD.
//   degS: range-partitioned LDS histograms, coalesced merge.
// BCAP: mean bucket load = E/196 = 4081, sigma ~= 64 -> 5120 = 16 sigma slack.

#define NBKT 256
#define BCAP 5120
#define CHUNK 2048
#define RB 12544   // deg-histogram bins per range (x4B = 49KB LDS)

// ---------------- Phase A: coarse binning by dst>>8 ----------------
__global__ __launch_bounds__(256) void binA_kernel(const int* __restrict__ ei,
                                                   int* __restrict__ gcur,
                                                   uint64_t* __restrict__ pairs,
                                                   int E) {
    __shared__ uint64_t stage[CHUNK];
    __shared__ int cnt[NBKT], obase[NBKT], goff[NBKT], curs[NBKT];
    __shared__ int wpart[4], stot;
    int t = threadIdx.x, lane = t & 63, wv = t >> 6;
    int e0 = blockIdx.x * CHUNK;
    int s[8], d[8];
    bool val[8];
#pragma unroll
    for (int j = 0; j < 8; ++j) {
        int e = e0 + j * 256 + t;
        val[j] = e < E;
        s[j] = val[j] ? ei[e] : 0;
        d[j] = val[j] ? ei[E + e] : 0;
    }
    cnt[t] = 0;
    __syncthreads();
#pragma unroll
    for (int j = 0; j < 8; ++j)
        if (val[j]) atomicAdd(&cnt[d[j] >> 8], 1);
    __syncthreads();
    // 256-bin exclusive scan (4 waves)
    int cv = cnt[t];
    int v = cv;
#pragma unroll
    for (int dd = 1; dd < 64; dd <<= 1) {
        int u = __shfl_up(v, dd);
        if (lane >= dd) v += u;
    }
    if (lane == 63) wpart[wv] = v;
    __syncthreads();
    if (t == 0) {
        int r = 0;
#pragma unroll
        for (int w = 0; w < 4; ++w) { int tmp = wpart[w]; wpart[w] = r; r += tmp; }
        stot = r;
    }
    __syncthreads();
    int eb = wpart[wv] + v - cv;
    obase[t] = eb;
    curs[t] = eb;
    goff[t] = (cv > 0) ? atomicAdd(&gcur[t], cv) : 0;
    __syncthreads();
    // place into LDS stage grouped by bucket
#pragma unroll
    for (int j = 0; j < 8; ++j)
        if (val[j]) {
            int b = d[j] >> 8;
            int pos = atomicAdd(&curs[b], 1);
            stage[pos] = ((uint64_t)(uint32_t)d[j] << 32) | (uint32_t)s[j];
        }
    __syncthreads();
    // coalesced flush to global bucket regions
    int tot = stot;
    for (int k = t; k < tot; k += 256) {
        uint64_t u = stage[k];
        int b = (int)(u >> 40);
        int slot = goff[b] + (k - obase[b]);
        if (slot < BCAP) pairs[(size_t)b * BCAP + slot] = u;
    }
}

// ---------------- Phase B: per-bucket CSR build ----------------
__global__ __launch_bounds__(256) void binB_kernel(const int* __restrict__ gcur,
                                                   const uint64_t* __restrict__ pairs,
                                                   int* __restrict__ csr,
                                                   int* __restrict__ rowptr,
                                                   int* __restrict__ cntD, int n) {
    __shared__ int hist[NBKT], obase[NBKT], curs[NBKT];
    __shared__ int wpart[4];
    int t = threadIdx.x, lane = t & 63, wv = t >> 6;
    int b = blockIdx.x;
    int nb = gcur[b]; if (nb > BCAP) nb = BCAP;
    hist[t] = 0;
    __syncthreads();
    const uint64_t* bp = pairs + (size_t)b * BCAP;
    for (int k = t; k < nb; k += 256) {
        int ld = (int)((bp[k] >> 32) & 255);
        atomicAdd(&hist[ld], 1);
    }
    __syncthreads();
    int cv = hist[t];
    int v = cv;
#pragma unroll
    for (int dd = 1; dd < 64; dd <<= 1) {
        int u = __shfl_up(v, dd);
        if (lane >= dd) v += u;
    }
    if (lane == 63) wpart[wv] = v;
    __syncthreads();
    if (t == 0) {
        int r = 0;
#pragma unroll
        for (int w = 0; w < 4; ++w) { int tmp = wpart[w]; wpart[w] = r; r += tmp; }
    }
    __syncthreads();
    int eb = wpart[wv] + v - cv;
    obase[t] = eb;
    curs[t] = eb;
    int node = b * 256 + t;
    if (node < n) {
        rowptr[node] = b * BCAP + eb;
        cntD[node] = cv;
    }
    __syncthreads();
    for (int k = t; k < nb; k += 256) {
        uint64_t u = bp[k];
        int ld = (int)((u >> 32) & 255);
        int pos = atomicAdd(&curs[ld], 1);
        csr[(size_t)b * BCAP + pos] = (int)(uint32_t)u;
    }
}

// ---------------- degree histogram (src), range-partitioned ----------------
__global__ __launch_bounds__(256) void deghist_kernel(const int* __restrict__ ei,
                                                      float* __restrict__ degS,
                                                      int E, int n, int R) {
    __shared__ int bins[RB];
    int t = threadIdx.x;
    int r = blockIdx.x % R;
    int sl = blockIdx.x / R;        // 16 slices
    int lo = r * RB;
    for (int i = t; i < RB; i += 256) bins[i] = 0;
    __syncthreads();
    int per = (E + 15) / 16;
    int b0 = sl * per, b1 = b0 + per; if (b1 > E) b1 = E;
    for (int e = b0 + t; e < b1; e += 256) {
        int s = ei[e] - lo;
        if (s >= 0 && s < RB) atomicAdd(&bins[s], 1);
    }
    __syncthreads();
    for (int i = t; i < RB; i += 256) {
        int vv = bins[i];
        if (vv && lo + i < n) atomicAdd(&degS[lo + i], (float)vv);
    }
}

__global__ __launch_bounds__(256) void dis_kernel(float* __restrict__ deg, int n) {
    int i = blockIdx.x * 256 + threadIdx.x;
    if (i < n) {
        float d = deg[i];
        deg[i] = (d > 0.0f) ? rsqrtf(d) : 0.0f;
    }
}

// ---- triple GEMM: h = relu(x@W1+b1); p0 = h@W20+b2; g = h@W21 ----
__global__ __launch_bounds__(256) void gemm3_kernel(const float* __restrict__ x,
                                                    const float* __restrict__ W1,
                                                    const float* __restrict__ b1,
                                                    const float* __restrict__ W20,
                                                    const float* __restrict__ W21,
                                                    const float* __restrict__ b2,
                                                    float* __restrict__ h,
                                                    float* __restrict__ p0,
                                                    float* __restrict__ g, int n) {
    __shared__ __align__(16) float sA[64][68];
    __shared__ __align__(16) float sW1[64][64];
    __shared__ __align__(16) float sW20[64][64];
    __shared__ __align__(16) float sW21[64][64];
    int t = threadIdx.x;
    for (int i = t; i < 4096; i += 256) {
        sW1[i >> 6][i & 63] = W1[i];
        sW20[i >> 6][i & 63] = W20[i];
        sW21[i >> 6][i & 63] = W21[i];
    }
    int r0 = blockIdx.x * 64;
    {
        int rr0 = t >> 4, k0 = (t & 15) * 4;
        for (int rr = rr0; rr < 64; rr += 16) {
            int grow = r0 + rr;
            float4 v = make_float4(0.f, 0.f, 0.f, 0.f);
            if (grow < n) v = *(const float4*)&x[(size_t)grow * 64 + k0];
            sA[k0][rr] = v.x; sA[k0 + 1][rr] = v.y;
            sA[k0 + 2][rr] = v.z; sA[k0 + 3][rr] = v.w;
        }
    }
    __syncthreads();
    int tr = t >> 4, tc = t & 15;

    float acc[4][4] = {};
    for (int k = 0; k < 64; ++k) {
        float4 a = *(const float4*)&sA[k][tr * 4];
        float4 b = *(const float4*)&sW1[k][tc * 4];
        float av[4] = {a.x, a.y, a.z, a.w};
        float bv[4] = {b.x, b.y, b.z, b.w};
#pragma unroll
        for (int i = 0; i < 4; ++i)
#pragma unroll
            for (int j = 0; j < 4; ++j) acc[i][j] = fmaf(av[i], bv[j], acc[i][j]);
    }
    float4 bv1 = *(const float4*)&b1[tc * 4];
    float hv[4][4];
#pragma unroll
    for (int i = 0; i < 4; ++i) {
        hv[i][0] = fmaxf(acc[i][0] + bv1.x, 0.f);
        hv[i][1] = fmaxf(acc[i][1] + bv1.y, 0.f);
        hv[i][2] = fmaxf(acc[i][2] + bv1.z, 0.f);
        hv[i][3] = fmaxf(acc[i][3] + bv1.w, 0.f);
    }
#pragma unroll
    for (int i = 0; i < 4; ++i) {
        int grow = r0 + tr * 4 + i;
        if (grow < n) {
            float4 o = make_float4(hv[i][0], hv[i][1], hv[i][2], hv[i][3]);
            *(float4*)&h[(size_t)grow * 64 + tc * 4] = o;
        }
    }
    __syncthreads();
#pragma unroll
    for (int i = 0; i < 4; ++i)
#pragma unroll
        for (int j = 0; j < 4; ++j) sA[tc * 4 + j][tr * 4 + i] = hv[i][j];
    __syncthreads();

    float accP[4][4] = {}, accG[4][4] = {};
    for (int k = 0; k < 64; ++k) {
        float4 a = *(const float4*)&sA[k][tr * 4];
        float4 bp = *(const float4*)&sW20[k][tc * 4];
        float4 bg = *(const float4*)&sW21[k][tc * 4];
        float av[4] = {a.x, a.y, a.z, a.w};
        float bpv[4] = {bp.x, bp.y, bp.z, bp.w};
        float bgv[4] = {bg.x, bg.y, bg.z, bg.w};
#pragma unroll
        for (int i = 0; i < 4; ++i)
#pragma unroll
            for (int j = 0; j < 4; ++j) {
                accP[i][j] = fmaf(av[i], bpv[j], accP[i][j]);
                accG[i][j] = fmaf(av[i], bgv[j], accG[i][j]);
            }
    }
    float4 bv2 = *(const float4*)&b2[tc * 4];
#pragma unroll
    for (int i = 0; i < 4; ++i) {
        int grow = r0 + tr * 4 + i;
        if (grow < n) {
            float4 op = make_float4(accP[i][0] + bv2.x, accP[i][1] + bv2.y,
                                    accP[i][2] + bv2.z, accP[i][3] + bv2.w);
            float4 og = make_float4(accG[i][0], accG[i][1], accG[i][2], accG[i][3]);
            *(float4*)&p0[(size_t)grow * 64 + tc * 4] = op;
            *(float4*)&g[(size_t)grow * 64 + tc * 4] = og;
        }
    }
}

// ---- gather + epilogue: lap, h2, 64->10 projection, log_softmax ----
__global__ __launch_bounds__(256) void gather_out_kernel(
        const int* __restrict__ rowptr, const int* __restrict__ cntD,
        const int* __restrict__ csr, const float* __restrict__ dis,
        const float* __restrict__ g, const float* __restrict__ p0,
        const float* __restrict__ h, const float* __restrict__ Wl,
        const float* __restrict__ bl, float* __restrict__ out, int n) {
    int c = threadIdx.x & 63;
    int row = blockIdx.x * 4 + (threadIdx.x >> 6);
    if (row >= n) return;
    float wl[10];
#pragma unroll
    for (int j = 0; j < 10; ++j) wl[j] = Wl[c * 10 + j];
    int m = cntD[row], rs = rowptr[row];
    float disd = dis[row];
    float a0 = 0.f, a1 = 0.f, a2 = 0.f, a3 = 0.f;
    for (int j0 = 0; j0 < m; j0 += 64) {
        int mm = m - j0; if (mm > 64) mm = 64;
        int idx = (c < mm) ? csr[rs + j0 + c] : 0;
        float dsl = (c < mm) ? dis[idx] : 0.f;
        int k = 0;
        for (; k + 4 <= mm; k += 4) {
            int s0 = __shfl(idx, k), s1 = __shfl(idx, k + 1);
            int s2 = __shfl(idx, k + 2), s3 = __shfl(idx, k + 3);
            float w0 = __shfl(dsl, k), w1 = __shfl(dsl, k + 1);
            float w2 = __shfl(dsl, k + 2), w3 = __shfl(dsl, k + 3);
            a0 = fmaf(w0, g[(size_t)s0 * 64 + c], a0);
            a1 = fmaf(w1, g[(size_t)s1 * 64 + c], a1);
            a2 = fmaf(w2, g[(size_t)s2 * 64 + c], a2);
            a3 = fmaf(w3, g[(size_t)s3 * 64 + c], a3);
        }
        for (; k < mm; ++k) {
            int s0 = __shfl(idx, k);
            float w0 = __shfl(dsl, k);
            a0 = fmaf(w0, g[(size_t)s0 * 64 + c], a0);
        }
    }
    float lv = -disd * ((a0 + a1) + (a2 + a3));
    float pv = p0[(size_t)row * 64 + c];
    float hv = h[(size_t)row * 64 + c];
    float h2 = fmaxf(pv + lv, 0.f) + hv;

    float mmax = -1e30f, myout = 0.f;
#pragma unroll
    for (int j = 0; j < 10; ++j) {
        float p = h2 * wl[j];
#pragma unroll
        for (int mk = 1; mk < 64; mk <<= 1) p += __shfl_xor(p, mk);
        p += bl[j];
        if (c == j) myout = p;
        mmax = fmaxf(mmax, p);
    }
    float ev = (c < 10) ? expf(myout - mmax) : 0.f;
#pragma unroll
    for (int mk = 1; mk < 64; mk <<= 1) ev += __shfl_xor(ev, mk);
    if (c < 10) out[(size_t)row * 10 + c] = myout - mmax - logf(ev);
}

extern "C" void kernel_launch(void* const* d_in, const int* in_sizes, int n_in,
                              void* d_out, int out_size, void* d_ws, size_t ws_size,
                              hipStream_t stream) {
    const float* x   = (const float*)d_in[0];
    const int*   ei  = (const int*)d_in[1];
    const float* W1  = (const float*)d_in[2];
    const float* b1  = (const float*)d_in[3];
    const float* W20 = (const float*)d_in[4];
    const float* W21 = (const float*)d_in[5];
    const float* b2  = (const float*)d_in[6];
    const float* Wl  = (const float*)d_in[7];
    const float* bl  = (const float*)d_in[8];
    float* out = (float*)d_out;

    int n = in_sizes[0] / 64;   // 50000
    int E = in_sizes[1] / 2;    // 800000

    char* ws = (char*)d_ws;
    size_t off = 0;
    auto alloc = [&](size_t bytes) {
        void* p = ws + off;
        off = (off + bytes + 255) & ~(size_t)255;
        return p;
    };
    int*      gcur   = (int*)alloc((size_t)NBKT * 4);
    uint64_t* pairs  = (uint64_t*)alloc((size_t)NBKT * BCAP * 8);   // 10.5 MB
    int*      csr    = (int*)alloc((size_t)NBKT * BCAP * 4);        // 5.2 MB
    int*      rowptr = (int*)alloc((size_t)n * 4);
    int*      cntD   = (int*)alloc((size_t)n * 4);
    float*    degS   = (float*)alloc((size_t)n * 4);                // -> dis
    float*    h      = (float*)alloc((size_t)n * 64 * 4);
    float*    p0     = (float*)alloc((size_t)n * 64 * 4);
    float*    g      = (float*)alloc((size_t)n * 64 * 4);

    hipMemsetAsync(gcur, 0, (size_t)NBKT * 4, stream);
    hipMemsetAsync(degS, 0, (size_t)n * 4, stream);

    int nchunk = (E + CHUNK - 1) / CHUNK;
    binA_kernel<<<nchunk, 256, 0, stream>>>(ei, gcur, pairs, E);
    binB_kernel<<<NBKT, 256, 0, stream>>>(gcur, pairs, csr, rowptr, cntD, n);
    int R = (n + RB - 1) / RB;
    deghist_kernel<<<R * 16, 256, 0, stream>>>(ei, degS, E, n, R);
    dis_kernel<<<(n + 255) / 256, 256, 0, stream>>>(degS, n);
    gemm3_kernel<<<(n + 63) / 64, 256, 0, stream>>>(x, W1, b1, W20, W21, b2, h, p0, g, n);
    gather_out_kernel<<<(n + 3) / 4, 256, 0, stream>>>(rowptr, cntD, csr, degS, g, p0,
                                                       h, Wl, bl, out, n);
}

// Round 6
// 220.848 us; speedup vs baseline: 1.1423x; 1.1423x over previous
//
#include <hip/hip_runtime.h>
#include <math.h>
#include <stdint.h>

// ChebConv GNN: N=50000, E=800000, F=H=64, C=10.
//   degI[i] = out-degree of i ; dis = rsqrt(degI) (0 if 0)
//   h  = relu(x @ W1 + b1)
//   p0 = h @ W20 + b2 ;  g = h @ W21
//   lap[dst] = sum_e -(dis[src]*dis[dst]) * g[src]   (CSR gather)
//   out = log_softmax( (relu(p0 + lap) + h) @ Wl + bl )
//
// Build: two-level LDS counting sort (no random global atomics for CSR).
//   Phase A: bin edges by dst>>8 into 256 bucket regions (coalesced flush)
//            + direct global int atomics for src-degree (low contention).
//   Phase B: per bucket (<=256 dsts), LDS histogram+scan -> CSR, rowptr, cntD.
// BCAP: mean bucket load = E/196 = 4081, sigma ~= 64 -> 5120 = 16 sigma slack.

#define NBKT 256
#define BCAP 5120
#define CHUNK 2048

// ---------------- Phase A: coarse binning by dst>>8 + src degree ----------------
__global__ __launch_bounds__(256) void binA_kernel(const int* __restrict__ ei,
                                                   int* __restrict__ gcur,
                                                   uint64_t* __restrict__ pairs,
                                                   int* __restrict__ degI,
                                                   int E) {
    __shared__ uint64_t stage[CHUNK];
    __shared__ int cnt[NBKT], obase[NBKT], goff[NBKT], curs[NBKT];
    __shared__ int wpart[4], stot;
    int t = threadIdx.x, lane = t & 63, wv = t >> 6;
    int e0 = blockIdx.x * CHUNK;
    int s[8], d[8];
    bool val[8];
#pragma unroll
    for (int j = 0; j < 8; ++j) {
        int e = e0 + j * 256 + t;
        val[j] = e < E;
        s[j] = val[j] ? ei[e] : 0;
        d[j] = val[j] ? ei[E + e] : 0;
    }
    cnt[t] = 0;
    __syncthreads();
#pragma unroll
    for (int j = 0; j < 8; ++j)
        if (val[j]) {
            atomicAdd(&cnt[d[j] >> 8], 1);
            atomicAdd(&degI[s[j]], 1);     // src out-degree (low contention)
        }
    __syncthreads();
    // 256-bin exclusive scan (4 waves)
    int cv = cnt[t];
    int v = cv;
#pragma unroll
    for (int dd = 1; dd < 64; dd <<= 1) {
        int u = __shfl_up(v, dd);
        if (lane >= dd) v += u;
    }
    if (lane == 63) wpart[wv] = v;
    __syncthreads();
    if (t == 0) {
        int r = 0;
#pragma unroll
        for (int w = 0; w < 4; ++w) { int tmp = wpart[w]; wpart[w] = r; r += tmp; }
        stot = r;
    }
    __syncthreads();
    int eb = wpart[wv] + v - cv;
    obase[t] = eb;
    curs[t] = eb;
    goff[t] = (cv > 0) ? atomicAdd(&gcur[t], cv) : 0;
    __syncthreads();
    // place into LDS stage grouped by bucket
#pragma unroll
    for (int j = 0; j < 8; ++j)
        if (val[j]) {
            int b = d[j] >> 8;
            int pos = atomicAdd(&curs[b], 1);
            stage[pos] = ((uint64_t)(uint32_t)d[j] << 32) | (uint32_t)s[j];
        }
    __syncthreads();
    // coalesced flush to global bucket regions
    int tot = stot;
    for (int k = t; k < tot; k += 256) {
        uint64_t u = stage[k];
        int b = (int)(u >> 40);
        int slot = goff[b] + (k - obase[b]);
        if (slot < BCAP) pairs[(size_t)b * BCAP + slot] = u;
    }
}

// ---------------- Phase B: per-bucket CSR build ----------------
__global__ __launch_bounds__(256) void binB_kernel(const int* __restrict__ gcur,
                                                   const uint64_t* __restrict__ pairs,
                                                   int* __restrict__ csr,
                                                   int* __restrict__ rowptr,
                                                   int* __restrict__ cntD, int n) {
    __shared__ int hist[NBKT], obase[NBKT], curs[NBKT];
    __shared__ int wpart[4];
    int t = threadIdx.x, lane = t & 63, wv = t >> 6;
    int b = blockIdx.x;
    int nb = gcur[b]; if (nb > BCAP) nb = BCAP;
    hist[t] = 0;
    __syncthreads();
    const uint64_t* bp = pairs + (size_t)b * BCAP;
    for (int k = t; k < nb; k += 256) {
        int ld = (int)((bp[k] >> 32) & 255);
        atomicAdd(&hist[ld], 1);
    }
    __syncthreads();
    int cv = hist[t];
    int v = cv;
#pragma unroll
    for (int dd = 1; dd < 64; dd <<= 1) {
        int u = __shfl_up(v, dd);
        if (lane >= dd) v += u;
    }
    if (lane == 63) wpart[wv] = v;
    __syncthreads();
    if (t == 0) {
        int r = 0;
#pragma unroll
        for (int w = 0; w < 4; ++w) { int tmp = wpart[w]; wpart[w] = r; r += tmp; }
    }
    __syncthreads();
    int eb = wpart[wv] + v - cv;
    obase[t] = eb;
    curs[t] = eb;
    int node = b * 256 + t;
    if (node < n) {
        rowptr[node] = b * BCAP + eb;
        cntD[node] = cv;
    }
    __syncthreads();
    for (int k = t; k < nb; k += 256) {
        uint64_t u = bp[k];
        int ld = (int)((u >> 32) & 255);
        int pos = atomicAdd(&curs[ld], 1);
        csr[(size_t)b * BCAP + pos] = (int)(uint32_t)u;
    }
}

__global__ __launch_bounds__(256) void dis_kernel(const int* __restrict__ degI,
                                                  float* __restrict__ dis, int n) {
    int i = blockIdx.x * 256 + threadIdx.x;
    if (i < n) {
        int d = degI[i];
        dis[i] = (d > 0) ? rsqrtf((float)d) : 0.0f;
    }
}

// ---- triple GEMM: h = relu(x@W1+b1); p0 = h@W20+b2; g = h@W21 ----
__global__ __launch_bounds__(256) void gemm3_kernel(const float* __restrict__ x,
                                                    const float* __restrict__ W1,
                                                    const float* __restrict__ b1,
                                                    const float* __restrict__ W20,
                                                    const float* __restrict__ W21,
                                                    const float* __restrict__ b2,
                                                    float* __restrict__ h,
                                                    float* __restrict__ p0,
                                                    float* __restrict__ g, int n) {
    __shared__ __align__(16) float sA[64][68];
    __shared__ __align__(16) float sW1[64][64];
    __shared__ __align__(16) float sW20[64][64];
    __shared__ __align__(16) float sW21[64][64];
    int t = threadIdx.x;
    for (int i = t; i < 4096; i += 256) {
        sW1[i >> 6][i & 63] = W1[i];
        sW20[i >> 6][i & 63] = W20[i];
        sW21[i >> 6][i & 63] = W21[i];
    }
    int r0 = blockIdx.x * 64;
    {
        int rr0 = t >> 4, k0 = (t & 15) * 4;
        for (int rr = rr0; rr < 64; rr += 16) {
            int grow = r0 + rr;
            float4 v = make_float4(0.f, 0.f, 0.f, 0.f);
            if (grow < n) v = *(const float4*)&x[(size_t)grow * 64 + k0];
            sA[k0][rr] = v.x; sA[k0 + 1][rr] = v.y;
            sA[k0 + 2][rr] = v.z; sA[k0 + 3][rr] = v.w;
        }
    }
    __syncthreads();
    int tr = t >> 4, tc = t & 15;

    float acc[4][4] = {};
    for (int k = 0; k < 64; ++k) {
        float4 a = *(const float4*)&sA[k][tr * 4];
        float4 b = *(const float4*)&sW1[k][tc * 4];
        float av[4] = {a.x, a.y, a.z, a.w};
        float bv[4] = {b.x, b.y, b.z, b.w};
#pragma unroll
        for (int i = 0; i < 4; ++i)
#pragma unroll
            for (int j = 0; j < 4; ++j) acc[i][j] = fmaf(av[i], bv[j], acc[i][j]);
    }
    float4 bv1 = *(const float4*)&b1[tc * 4];
    float hv[4][4];
#pragma unroll
    for (int i = 0; i < 4; ++i) {
        hv[i][0] = fmaxf(acc[i][0] + bv1.x, 0.f);
        hv[i][1] = fmaxf(acc[i][1] + bv1.y, 0.f);
        hv[i][2] = fmaxf(acc[i][2] + bv1.z, 0.f);
        hv[i][3] = fmaxf(acc[i][3] + bv1.w, 0.f);
    }
#pragma unroll
    for (int i = 0; i < 4; ++i) {
        int grow = r0 + tr * 4 + i;
        if (grow < n) {
            float4 o = make_float4(hv[i][0], hv[i][1], hv[i][2], hv[i][3]);
            *(float4*)&h[(size_t)grow * 64 + tc * 4] = o;
        }
    }
    __syncthreads();
#pragma unroll
    for (int i = 0; i < 4; ++i)
#pragma unroll
        for (int j = 0; j < 4; ++j) sA[tc * 4 + j][tr * 4 + i] = hv[i][j];
    __syncthreads();

    float accP[4][4] = {}, accG[4][4] = {};
    for (int k = 0; k < 64; ++k) {
        float4 a = *(const float4*)&sA[k][tr * 4];
        float4 bp = *(const float4*)&sW20[k][tc * 4];
        float4 bg = *(const float4*)&sW21[k][tc * 4];
        float av[4] = {a.x, a.y, a.z, a.w};
        float bpv[4] = {bp.x, bp.y, bp.z, bp.w};
        float bgv[4] = {bg.x, bg.y, bg.z, bg.w};
#pragma unroll
        for (int i = 0; i < 4; ++i)
#pragma unroll
            for (int j = 0; j < 4; ++j) {
                accP[i][j] = fmaf(av[i], bpv[j], accP[i][j]);
                accG[i][j] = fmaf(av[i], bgv[j], accG[i][j]);
            }
    }
    float4 bv2 = *(const float4*)&b2[tc * 4];
#pragma unroll
    for (int i = 0; i < 4; ++i) {
        int grow = r0 + tr * 4 + i;
        if (grow < n) {
            float4 op = make_float4(accP[i][0] + bv2.x, accP[i][1] + bv2.y,
                                    accP[i][2] + bv2.z, accP[i][3] + bv2.w);
            float4 og = make_float4(accG[i][0], accG[i][1], accG[i][2], accG[i][3]);
            *(float4*)&p0[(size_t)grow * 64 + tc * 4] = op;
            *(float4*)&g[(size_t)grow * 64 + tc * 4] = og;
        }
    }
}

// ---- gather + epilogue: lap, h2, 64->10 projection, log_softmax ----
__global__ __launch_bounds__(256) void gather_out_kernel(
        const int* __restrict__ rowptr, const int* __restrict__ cntD,
        const int* __restrict__ csr, const float* __restrict__ dis,
        const float* __restrict__ g, const float* __restrict__ p0,
        const float* __restrict__ h, const float* __restrict__ Wl,
        const float* __restrict__ bl, float* __restrict__ out, int n) {
    int c = threadIdx.x & 63;
    int row = blockIdx.x * 4 + (threadIdx.x >> 6);
    if (row >= n) return;
    float wl[10];
#pragma unroll
    for (int j = 0; j < 10; ++j) wl[j] = Wl[c * 10 + j];
    int m = cntD[row], rs = rowptr[row];
    float disd = dis[row];
    float a0 = 0.f, a1 = 0.f, a2 = 0.f, a3 = 0.f;
    for (int j0 = 0; j0 < m; j0 += 64) {
        int mm = m - j0; if (mm > 64) mm = 64;
        int idx = (c < mm) ? csr[rs + j0 + c] : 0;
        float dsl = (c < mm) ? dis[idx] : 0.f;
        int k = 0;
        for (; k + 4 <= mm; k += 4) {
            int s0 = __shfl(idx, k), s1 = __shfl(idx, k + 1);
            int s2 = __shfl(idx, k + 2), s3 = __shfl(idx, k + 3);
            float w0 = __shfl(dsl, k), w1 = __shfl(dsl, k + 1);
            float w2 = __shfl(dsl, k + 2), w3 = __shfl(dsl, k + 3);
            a0 = fmaf(w0, g[(size_t)s0 * 64 + c], a0);
            a1 = fmaf(w1, g[(size_t)s1 * 64 + c], a1);
            a2 = fmaf(w2, g[(size_t)s2 * 64 + c], a2);
            a3 = fmaf(w3, g[(size_t)s3 * 64 + c], a3);
        }
        for (; k < mm; ++k) {
            int s0 = __shfl(idx, k);
            float w0 = __shfl(dsl, k);
            a0 = fmaf(w0, g[(size_t)s0 * 64 + c], a0);
        }
    }
    float lv = -disd * ((a0 + a1) + (a2 + a3));
    float pv = p0[(size_t)row * 64 + c];
    float hv = h[(size_t)row * 64 + c];
    float h2 = fmaxf(pv + lv, 0.f) + hv;

    float mmax = -1e30f, myout = 0.f;
#pragma unroll
    for (int j = 0; j < 10; ++j) {
        float p = h2 * wl[j];
#pragma unroll
        for (int mk = 1; mk < 64; mk <<= 1) p += __shfl_xor(p, mk);
        p += bl[j];
        if (c == j) myout = p;
        mmax = fmaxf(mmax, p);
    }
    float ev = (c < 10) ? expf(myout - mmax) : 0.f;
#pragma unroll
    for (int mk = 1; mk < 64; mk <<= 1) ev += __shfl_xor(ev, mk);
    if (c < 10) out[(size_t)row * 10 + c] = myout - mmax - logf(ev);
}

extern "C" void kernel_launch(void* const* d_in, const int* in_sizes, int n_in,
                              void* d_out, int out_size, void* d_ws, size_t ws_size,
                              hipStream_t stream) {
    const float* x   = (const float*)d_in[0];
    const int*   ei  = (const int*)d_in[1];
    const float* W1  = (const float*)d_in[2];
    const float* b1  = (const float*)d_in[3];
    const float* W20 = (const float*)d_in[4];
    const float* W21 = (const float*)d_in[5];
    const float* b2  = (const float*)d_in[6];
    const float* Wl  = (const float*)d_in[7];
    const float* bl  = (const float*)d_in[8];
    float* out = (float*)d_out;

    int n = in_sizes[0] / 64;   // 50000
    int E = in_sizes[1] / 2;    // 800000

    char* ws = (char*)d_ws;
    size_t off = 0;
    auto alloc = [&](size_t bytes) {
        void* p = ws + off;
        off = (off + bytes + 255) & ~(size_t)255;
        return p;
    };
    int*      gcur   = (int*)alloc((size_t)NBKT * 4);
    uint64_t* pairs  = (uint64_t*)alloc((size_t)NBKT * BCAP * 8);   // 10.5 MB
    int*      csr    = (int*)alloc((size_t)NBKT * BCAP * 4);        // 5.2 MB
    int*      rowptr = (int*)alloc((size_t)n * 4);
    int*      cntD   = (int*)alloc((size_t)n * 4);
    int*      degI   = (int*)alloc((size_t)n * 4);
    float*    dis    = (float*)alloc((size_t)n * 4);
    float*    h      = (float*)alloc((size_t)n * 64 * 4);
    float*    p0     = (float*)alloc((size_t)n * 64 * 4);
    float*    g      = (float*)alloc((size_t)n * 64 * 4);

    hipMemsetAsync(gcur, 0, (size_t)NBKT * 4, stream);
    hipMemsetAsync(degI, 0, (size_t)n * 4, stream);

    int nchunk = (E + CHUNK - 1) / CHUNK;
    binA_kernel<<<nchunk, 256, 0, stream>>>(ei, gcur, pairs, degI, E);
    binB_kernel<<<NBKT, 256, 0, stream>>>(gcur, pairs, csr, rowptr, cntD, n);
    dis_kernel<<<(n + 255) / 256, 256, 0, stream>>>(degI, dis, n);
    gemm3_kernel<<<(n + 63) / 64, 256, 0, stream>>>(x, W1, b1, W20, W21, b2, h, p0, g, n);
    gather_out_kernel<<<(n + 3) / 4, 256, 0, stream>>>(rowptr, cntD, csr, dis, g, p0,
                                                       h, Wl, bl, out, n);
}

// Round 7
// 209.959 us; speedup vs baseline: 1.2016x; 1.0519x over previous
//
#include <hip/hip_runtime.h>
#include <math.h>
#include <stdint.h>

// ChebConv GNN: N=50000, E=800000, F=H=64, C=10.
//   degI[i] = out-degree of i ; dis = rsqrt(degI) (0 if 0)
//   h  = relu(x @ W1 + b1)
//   p0 = h @ W20 + b2 ;  g' = dis[row] * (h @ W21)   (prescaled!)
//   lap[dst] = -dis[dst] * sum_{src in N(dst)} g'[src]    (unweighted CSR gather)
//   out = log_softmax( (relu(p0 + lap) + h) @ Wl + bl )
//
// Build: two-level LDS counting sort (no random global atomics for CSR).
//   Phase A: bin edges by dst>>8 into 256 bucket regions (coalesced flush)
//            + XCD-privatized degree atomics (degI8[blockIdx&7][src]).
//   Phase B: per bucket (<=256 dsts), LDS histogram+scan -> CSR, rowptr, cntD.
// BCAP: mean bucket load = E/196 = 4081, sigma ~= 64 -> 5120 = 16 sigma slack.

#define NBKT 256
#define BCAP 5120
#define CHUNK 2048

// ---------------- Phase A: coarse binning by dst>>8 + src degree ----------------
__global__ __launch_bounds__(256) void binA_kernel(const int* __restrict__ ei,
                                                   int* __restrict__ gcur,
                                                   uint64_t* __restrict__ pairs,
                                                   int* __restrict__ degI8,
                                                   int E, int n) {
    __shared__ uint64_t stage[CHUNK];
    __shared__ int cnt[NBKT], obase[NBKT], goff[NBKT], curs[NBKT];
    __shared__ int wpart[4], stot;
    int t = threadIdx.x, lane = t & 63, wv = t >> 6;
    int e0 = blockIdx.x * CHUNK;
    int* degP = degI8 + (size_t)(blockIdx.x & 7) * n;   // XCD-private copy
    int s[8], d[8];
    bool val[8];
#pragma unroll
    for (int j = 0; j < 8; ++j) {
        int e = e0 + j * 256 + t;
        val[j] = e < E;
        s[j] = val[j] ? ei[e] : 0;
        d[j] = val[j] ? ei[E + e] : 0;
    }
    cnt[t] = 0;
    __syncthreads();
#pragma unroll
    for (int j = 0; j < 8; ++j)
        if (val[j]) {
            atomicAdd(&cnt[d[j] >> 8], 1);
            atomicAdd(&degP[s[j]], 1);     // src out-degree, XCD-local line
        }
    __syncthreads();
    // 256-bin exclusive scan (4 waves)
    int cv = cnt[t];
    int v = cv;
#pragma unroll
    for (int dd = 1; dd < 64; dd <<= 1) {
        int u = __shfl_up(v, dd);
        if (lane >= dd) v += u;
    }
    if (lane == 63) wpart[wv] = v;
    __syncthreads();
    if (t == 0) {
        int r = 0;
#pragma unroll
        for (int w = 0; w < 4; ++w) { int tmp = wpart[w]; wpart[w] = r; r += tmp; }
        stot = r;
    }
    __syncthreads();
    int eb = wpart[wv] + v - cv;
    obase[t] = eb;
    curs[t] = eb;
    goff[t] = (cv > 0) ? atomicAdd(&gcur[t], cv) : 0;
    __syncthreads();
    // place into LDS stage grouped by bucket
#pragma unroll
    for (int j = 0; j < 8; ++j)
        if (val[j]) {
            int b = d[j] >> 8;
            int pos = atomicAdd(&curs[b], 1);
            stage[pos] = ((uint64_t)(uint32_t)d[j] << 32) | (uint32_t)s[j];
        }
    __syncthreads();
    // coalesced flush to global bucket regions
    int tot = stot;
    for (int k = t; k < tot; k += 256) {
        uint64_t u = stage[k];
        int b = (int)(u >> 40);
        int slot = goff[b] + (k - obase[b]);
        if (slot < BCAP) pairs[(size_t)b * BCAP + slot] = u;
    }
}

// ---------------- Phase B: per-bucket CSR build ----------------
__global__ __launch_bounds__(256) void binB_kernel(const int* __restrict__ gcur,
                                                   const uint64_t* __restrict__ pairs,
                                                   int* __restrict__ csr,
                                                   int* __restrict__ rowptr,
                                                   int* __restrict__ cntD, int n) {
    __shared__ int hist[NBKT], obase[NBKT], curs[NBKT];
    __shared__ int wpart[4];
    int t = threadIdx.x, lane = t & 63, wv = t >> 6;
    int b = blockIdx.x;
    int nb = gcur[b]; if (nb > BCAP) nb = BCAP;
    hist[t] = 0;
    __syncthreads();
    const uint64_t* bp = pairs + (size_t)b * BCAP;
    for (int k = t; k < nb; k += 256) {
        int ld = (int)((bp[k] >> 32) & 255);
        atomicAdd(&hist[ld], 1);
    }
    __syncthreads();
    int cv = hist[t];
    int v = cv;
#pragma unroll
    for (int dd = 1; dd < 64; dd <<= 1) {
        int u = __shfl_up(v, dd);
        if (lane >= dd) v += u;
    }
    if (lane == 63) wpart[wv] = v;
    __syncthreads();
    if (t == 0) {
        int r = 0;
#pragma unroll
        for (int w = 0; w < 4; ++w) { int tmp = wpart[w]; wpart[w] = r; r += tmp; }
    }
    __syncthreads();
    int eb = wpart[wv] + v - cv;
    obase[t] = eb;
    curs[t] = eb;
    int node = b * 256 + t;
    if (node < n) {
        rowptr[node] = b * BCAP + eb;
        cntD[node] = cv;
    }
    __syncthreads();
    for (int k = t; k < nb; k += 256) {
        uint64_t u = bp[k];
        int ld = (int)((u >> 32) & 255);
        int pos = atomicAdd(&curs[ld], 1);
        csr[(size_t)b * BCAP + pos] = (int)(uint32_t)u;
    }
}

// ---------------- dis = rsqrt(sum of 8 private degree copies) ----------------
__global__ __launch_bounds__(256) void dis_kernel(const int* __restrict__ degI8,
                                                  float* __restrict__ dis, int n) {
    int i = blockIdx.x * 256 + threadIdx.x;
    if (i < n) {
        int d = 0;
#pragma unroll
        for (int j = 0; j < 8; ++j) d += degI8[(size_t)j * n + i];
        dis[i] = (d > 0) ? rsqrtf((float)d) : 0.0f;
    }
}

// ---- triple GEMM: h = relu(x@W1+b1); p0 = h@W20+b2; g' = dis*(h@W21) ----
__global__ __launch_bounds__(256) void gemm3_kernel(const float* __restrict__ x,
                                                    const float* __restrict__ W1,
                                                    const float* __restrict__ b1,
                                                    const float* __restrict__ W20,
                                                    const float* __restrict__ W21,
                                                    const float* __restrict__ b2,
                                                    const float* __restrict__ dis,
                                                    float* __restrict__ h,
                                                    float* __restrict__ p0,
                                                    float* __restrict__ g, int n) {
    __shared__ __align__(16) float sA[64][68];
    __shared__ __align__(16) float sW1[64][64];
    __shared__ __align__(16) float sW20[64][64];
    __shared__ __align__(16) float sW21[64][64];
    int t = threadIdx.x;
    for (int i = t; i < 4096; i += 256) {
        sW1[i >> 6][i & 63] = W1[i];
        sW20[i >> 6][i & 63] = W20[i];
        sW21[i >> 6][i & 63] = W21[i];
    }
    int r0 = blockIdx.x * 64;
    {
        int rr0 = t >> 4, k0 = (t & 15) * 4;
        for (int rr = rr0; rr < 64; rr += 16) {
            int grow = r0 + rr;
            float4 v = make_float4(0.f, 0.f, 0.f, 0.f);
            if (grow < n) v = *(const float4*)&x[(size_t)grow * 64 + k0];
            sA[k0][rr] = v.x; sA[k0 + 1][rr] = v.y;
            sA[k0 + 2][rr] = v.z; sA[k0 + 3][rr] = v.w;
        }
    }
    __syncthreads();
    int tr = t >> 4, tc = t & 15;

    float acc[4][4] = {};
    for (int k = 0; k < 64; ++k) {
        float4 a = *(const float4*)&sA[k][tr * 4];
        float4 b = *(const float4*)&sW1[k][tc * 4];
        float av[4] = {a.x, a.y, a.z, a.w};
        float bv[4] = {b.x, b.y, b.z, b.w};
#pragma unroll
        for (int i = 0; i < 4; ++i)
#pragma unroll
            for (int j = 0; j < 4; ++j) acc[i][j] = fmaf(av[i], bv[j], acc[i][j]);
    }
    float4 bv1 = *(const float4*)&b1[tc * 4];
    float hv[4][4];
#pragma unroll
    for (int i = 0; i < 4; ++i) {
        hv[i][0] = fmaxf(acc[i][0] + bv1.x, 0.f);
        hv[i][1] = fmaxf(acc[i][1] + bv1.y, 0.f);
        hv[i][2] = fmaxf(acc[i][2] + bv1.z, 0.f);
        hv[i][3] = fmaxf(acc[i][3] + bv1.w, 0.f);
    }
#pragma unroll
    for (int i = 0; i < 4; ++i) {
        int grow = r0 + tr * 4 + i;
        if (grow < n) {
            float4 o = make_float4(hv[i][0], hv[i][1], hv[i][2], hv[i][3]);
            *(float4*)&h[(size_t)grow * 64 + tc * 4] = o;
        }
    }
    __syncthreads();
#pragma unroll
    for (int i = 0; i < 4; ++i)
#pragma unroll
        for (int j = 0; j < 4; ++j) sA[tc * 4 + j][tr * 4 + i] = hv[i][j];
    __syncthreads();

    float accP[4][4] = {}, accG[4][4] = {};
    for (int k = 0; k < 64; ++k) {
        float4 a = *(const float4*)&sA[k][tr * 4];
        float4 bp = *(const float4*)&sW20[k][tc * 4];
        float4 bg = *(const float4*)&sW21[k][tc * 4];
        float av[4] = {a.x, a.y, a.z, a.w};
        float bpv[4] = {bp.x, bp.y, bp.z, bp.w};
        float bgv[4] = {bg.x, bg.y, bg.z, bg.w};
#pragma unroll
        for (int i = 0; i < 4; ++i)
#pragma unroll
            for (int j = 0; j < 4; ++j) {
                accP[i][j] = fmaf(av[i], bpv[j], accP[i][j]);
                accG[i][j] = fmaf(av[i], bgv[j], accG[i][j]);
            }
    }
    float4 bv2 = *(const float4*)&b2[tc * 4];
#pragma unroll
    for (int i = 0; i < 4; ++i) {
        int grow = r0 + tr * 4 + i;
        if (grow < n) {
            float dr = dis[grow];          // prescale g rows by dis[row]
            float4 op = make_float4(accP[i][0] + bv2.x, accP[i][1] + bv2.y,
                                    accP[i][2] + bv2.z, accP[i][3] + bv2.w);
            float4 og = make_float4(dr * accG[i][0], dr * accG[i][1],
                                    dr * accG[i][2], dr * accG[i][3]);
            *(float4*)&p0[(size_t)grow * 64 + tc * 4] = op;
            *(float4*)&g[(size_t)grow * 64 + tc * 4] = og;
        }
    }
}

// ---- gather + epilogue: lap, h2, 64->10 projection, log_softmax ----
// Wave-uniform csr reads (s_load) — no shfl, no per-edge weight.
__global__ __launch_bounds__(256) void gather_out_kernel(
        const int* __restrict__ rowptr, const int* __restrict__ cntD,
        const int* __restrict__ csr, const float* __restrict__ dis,
        const float* __restrict__ g, const float* __restrict__ p0,
        const float* __restrict__ h, const float* __restrict__ Wl,
        const float* __restrict__ bl, float* __restrict__ out, int n) {
    int c = threadIdx.x & 63;
    int row = blockIdx.x * 4 + (threadIdx.x >> 6);
    if (row >= n) return;
    float wl[10];
#pragma unroll
    for (int j = 0; j < 10; ++j) wl[j] = Wl[c * 10 + j];
    int m = cntD[row], rs = rowptr[row];     // wave-uniform
    float disd = dis[row];
    float pv = p0[(size_t)row * 64 + c];
    float hv = h[(size_t)row * 64 + c];

    float a0 = 0.f, a1 = 0.f, a2 = 0.f, a3 = 0.f;
    int k = 0;
    for (; k + 4 <= m; k += 4) {
        int s0 = csr[rs + k];                // uniform addr -> s_load
        int s1 = csr[rs + k + 1];
        int s2 = csr[rs + k + 2];
        int s3 = csr[rs + k + 3];
        a0 += g[(size_t)s0 * 64 + c];
        a1 += g[(size_t)s1 * 64 + c];
        a2 += g[(size_t)s2 * 64 + c];
        a3 += g[(size_t)s3 * 64 + c];
    }
    for (; k < m; ++k) {
        int s0 = csr[rs + k];
        a0 += g[(size_t)s0 * 64 + c];
    }
    float lv = -disd * ((a0 + a1) + (a2 + a3));
    float h2 = fmaxf(pv + lv, 0.f) + hv;

    float mmax = -1e30f, myout = 0.f;
#pragma unroll
    for (int j = 0; j < 10; ++j) {
        float p = h2 * wl[j];
#pragma unroll
        for (int mk = 1; mk < 64; mk <<= 1) p += __shfl_xor(p, mk);
        p += bl[j];
        if (c == j) myout = p;
        mmax = fmaxf(mmax, p);
    }
    float ev = (c < 10) ? expf(myout - mmax) : 0.f;
#pragma unroll
    for (int mk = 1; mk < 64; mk <<= 1) ev += __shfl_xor(ev, mk);
    if (c < 10) out[(size_t)row * 10 + c] = myout - mmax - logf(ev);
}

extern "C" void kernel_launch(void* const* d_in, const int* in_sizes, int n_in,
                              void* d_out, int out_size, void* d_ws, size_t ws_size,
                              hipStream_t stream) {
    const float* x   = (const float*)d_in[0];
    const int*   ei  = (const int*)d_in[1];
    const float* W1  = (const float*)d_in[2];
    const float* b1  = (const float*)d_in[3];
    const float* W20 = (const float*)d_in[4];
    const float* W21 = (const float*)d_in[5];
    const float* b2  = (const float*)d_in[6];
    const float* Wl  = (const float*)d_in[7];
    const float* bl  = (const float*)d_in[8];
    float* out = (float*)d_out;

    int n = in_sizes[0] / 64;   // 50000
    int E = in_sizes[1] / 2;    // 800000

    char* ws = (char*)d_ws;
    size_t off = 0;
    auto alloc = [&](size_t bytes) {
        void* p = ws + off;
        off = (off + bytes + 255) & ~(size_t)255;
        return p;
    };
    int*      gcur   = (int*)alloc((size_t)NBKT * 4);
    uint64_t* pairs  = (uint64_t*)alloc((size_t)NBKT * BCAP * 8);   // 10.5 MB
    int*      csr    = (int*)alloc((size_t)NBKT * BCAP * 4);        // 5.2 MB
    int*      rowptr = (int*)alloc((size_t)n * 4);
    int*      cntD   = (int*)alloc((size_t)n * 4);
    int*      degI8  = (int*)alloc((size_t)n * 8 * 4);              // 1.6 MB
    float*    dis    = (float*)alloc((size_t)n * 4);
    float*    h      = (float*)alloc((size_t)n * 64 * 4);
    float*    p0     = (float*)alloc((size_t)n * 64 * 4);
    float*    g      = (float*)alloc((size_t)n * 64 * 4);

    hipMemsetAsync(gcur, 0, (size_t)NBKT * 4, stream);
    hipMemsetAsync(degI8, 0, (size_t)n * 8 * 4, stream);

    int nchunk = (E + CHUNK - 1) / CHUNK;
    binA_kernel<<<nchunk, 256, 0, stream>>>(ei, gcur, pairs, degI8, E, n);
    dis_kernel<<<(n + 255) / 256, 256, 0, stream>>>(degI8, dis, n);
    binB_kernel<<<NBKT, 256, 0, stream>>>(gcur, pairs, csr, rowptr, cntD, n);
    gemm3_kernel<<<(n + 63) / 64, 256, 0, stream>>>(x, W1, b1, W20, W21, b2, dis,
                                                    h, p0, g, n);
    gather_out_kernel<<<(n + 3) / 4, 256, 0, stream>>>(rowptr, cntD, csr, dis, g, p0,
                                                       h, Wl, bl, out, n);
}